// Round 6
// baseline (241.843 us; speedup 1.0000x reference)
//
#include <hip/hip_runtime.h>

// Problem constants (B,C,H,W)=(2,256,56,56), Cr=64, K=7, G=16, stride=1
#define HW     3136          // 56*56
#define C_IN   256
#define CR     64
#define KKG    784           // 49*16
#define NB     2             // batch
#define NPIX   6272          // NB*HW
#define NT25   25            // p-tiles of 256 over NPIX
#define BN_EPS 1e-5f

// Device-global scratch (fully rewritten every call; no cross-call state)
__device__ float g_P[4 * CR * NPIX];       // K-split conv1 partials [kc][o][p]
__device__ float g_T[CR * NPIX];           // conv1 output (pre-BN) [o][p]
__device__ float g_bs[2 * CR * NT25];      // per-block partial sum/sumsq [2][o][px]
__device__ float g_xg[16 * NPIX * 16];     // x transposed: [d][p][cg] = x[b][16cg+d][hw]
__device__ float g_w2s[16 * 49 * CR];      // w2 regrouped: [s][kk][c] = w2[16kk+s][c]

// ---------------- K1a: conv1 partials (o-tile 8, split-K 4), XCD-swizzled ----------------
// grid (825) 1-D, block 256.  (ROUND-0 VERIFIED CODE -- do not restructure: the split-K
// "extra" 12.8 MB g_P round-trip buys 800 blocks of latency hiding; the 200-block
// full-K fusion (round 2) regressed 124->133 us.)
__global__ __launch_bounds__(256) void k1a_conv1(const float* __restrict__ x,
                                                 const float* __restrict__ w1,
                                                 const float* __restrict__ w2) {
  int bid = blockIdx.x;
  if (bid >= 800) {
    int t = bid - 800;
    int idx = t * 256 + threadIdx.x;
    for (int j = idx; j < 16 * 49 * CR; j += 25 * 256) {
      int s  = j / 3136;                   // 49*64 = 3136 per s
      int r  = j - s * 3136;
      int kk = r >> 6;
      int c  = r & 63;                     // g_w2s[s][kk][c] = w2[(16kk+s)*64 + c]
      g_w2s[j] = w2[(16 * kk + s) * CR + c];
    }
    return;
  }
  int kc     = (bid & 7) >> 1;              // constant per XCD-pair
  int parity = bid & 1;
  int unit   = (bid >> 3) * 2 + parity;     // [0, 200)
  int o0     = (unit & 7) * 8;
  int pt     = unit >> 3;                   // [0, 25)
  int p      = pt * 256 + threadIdx.x;
  if (p >= NPIX) return;
  int b = p / HW;
  int u = p - b * HW;

  const float* xb = x + ((size_t)(b * C_IN + kc * 64)) * HW + u;
  const float* w  = w1 + kc * 64;           // w1[o*256 + kc*64 + c]

  float acc[8];
#pragma unroll
  for (int i = 0; i < 8; ++i) acc[i] = 0.0f;
#pragma unroll 8
  for (int c = 0; c < 64; ++c) {
    float xv = xb[(size_t)c * HW];          // coalesced across lanes, L2-resident slice
#pragma unroll
    for (int i = 0; i < 8; ++i)
      acc[i] += w[(o0 + i) * C_IN + c] * xv;  // wave-uniform -> s_load
  }
  float* pp = g_P + ((size_t)kc * CR + o0) * NPIX + p;
#pragma unroll
  for (int i = 0; i < 8; ++i) pp[(size_t)i * NPIX] = acc[i];
}

// ---------------- kRT: fused (reduce partials -> T + partial stats) | (transpose x) ----
// grid (25, 80), block 256.  (ROUND-0 VERIFIED CODE.)
__global__ __launch_bounds__(256) void kRT(const float* __restrict__ x,
                                           const float* __restrict__ b1) {
  int p = blockIdx.x * 256 + threadIdx.x;
  if (blockIdx.y < 64) {
    int o = blockIdx.y;
    bool valid = (p < NPIX);
    float v = 0.0f;
    if (valid) {
      v = b1[o]
        + g_P[((size_t)0 * CR + o) * NPIX + p]
        + g_P[((size_t)1 * CR + o) * NPIX + p]
        + g_P[((size_t)2 * CR + o) * NPIX + p]
        + g_P[((size_t)3 * CR + o) * NPIX + p];
      g_T[(size_t)o * NPIX + p] = v;
    }
    float s  = valid ? v : 0.0f;
    float s2 = valid ? v * v : 0.0f;
#pragma unroll
    for (int off = 32; off > 0; off >>= 1) {
      s  += __shfl_down(s, off);
      s2 += __shfl_down(s2, off);
    }
    __shared__ float sd[8];
    int lane = threadIdx.x & 63, wid = threadIdx.x >> 6;
    if (lane == 0) { sd[wid] = s; sd[4 + wid] = s2; }
    __syncthreads();
    if (threadIdx.x == 0) {
      g_bs[o * NT25 + blockIdx.x]             = sd[0] + sd[1] + sd[2] + sd[3];
      g_bs[CR * NT25 + o * NT25 + blockIdx.x] = sd[4] + sd[5] + sd[6] + sd[7];
    }
  } else {
    int d = blockIdx.y - 64;
    if (p >= NPIX) return;
    int b  = (p >= HW) ? 1 : 0;
    int hw = p - b * HW;
    const float* xp = x + ((size_t)(b * C_IN + d)) * HW + hw;
    float r[16];
#pragma unroll
    for (int cg = 0; cg < 16; ++cg)
      r[cg] = xp[(size_t)cg * (16 * HW)];
    float4* dst = (float4*)(g_xg + (((size_t)d * NPIX + p) << 4));
    dst[0] = make_float4(r[0], r[1], r[2], r[3]);
    dst[1] = make_float4(r[4], r[5], r[6], r[7]);
    dst[2] = make_float4(r[8], r[9], r[10], r[11]);
    dst[3] = make_float4(r[12], r[13], r[14], r[15]);
  }
}

// ---------------- k45: FUSED conv2 + involution, PHASE-SPLIT, 128-thread blocks ---------
// Round-4 lesson: cg-split doubled conv2 FMA (the dominant VALU cost) -> 80.6 us. REVERT
// to compute-once. Round-3 residual (44.4 us, VALUBusy 18%): per-tap interleave
// {s_loads -> 64-FMA chain -> 1 vector load} gave the scheduler no independent loads to
// batch. This version, at IDENTICAL total FMA:
//   Phase 1: all 49 conv2 kv values, fully unrolled (kv[] in VGPRs, static indices),
//            stores kout (computed once -> round-3-identical bits).
//   Phase 2: 49 INDEPENDENT x_g 64B loads + 16 FMA each, fully unrolled -> deep
//            vmcnt-counted load batching.
//   Blocks of 128 (2 waves), grid (16,25,2)=800 blocks: same wave count, 3.1 blocks/CU
//   balances 3-vs-4 (was 416 blocks: 1-vs-2) -> higher time-avg occupancy, shorter tail.
// (Round-5 run was an infra failure -- container acquisition, no kernel signal --
//  resubmitted unchanged.)
__global__ __launch_bounds__(128) void k45(const float* __restrict__ gamma,
                                           const float* __restrict__ beta,
                                           const float* __restrict__ b2,
                                           float* __restrict__ kout,
                                           float* __restrict__ out) {
  // BN finalize (same math/order as before)
  __shared__ float ssc[CR], ssh[CR];
  if (threadIdx.x < CR) {
    int o = threadIdx.x;
    float S = 0.f, S2 = 0.f;
#pragma unroll
    for (int px = 0; px < NT25; ++px) {
      S  += g_bs[o * NT25 + px];
      S2 += g_bs[CR * NT25 + o * NT25 + px];
    }
    const float invN = 1.0f / (float)NPIX;
    float mean = S * invN;
    float var  = S2 * invN - mean * mean;   // population var matches jnp.var
    float inv  = rsqrtf(var + BN_EPS);
    float sc   = gamma[o] * inv;
    ssc[o] = sc;
    ssh[o] = beta[o] - mean * sc;
  }
  __syncthreads();

  int u = blockIdx.y * 128 + threadIdx.x;     // [0, 3200); last tile half-idle
  if (u >= HW) return;                        // after the barrier
  int s = blockIdx.x;                         // wave-uniform
  int b = blockIdx.z;

  // Stage this pixel's BN+ReLU'd conv1 column in registers (coalesced across lanes).
  float t_reg[CR];
  const float* Tb = g_T + (size_t)b * HW + u;
#pragma unroll
  for (int c = 0; c < CR; ++c)
    t_reg[c] = fmaxf(fmaf(Tb[(size_t)c * NPIX], ssc[c], ssh[c]), 0.0f);

  const float* wbase = g_w2s + (size_t)s * (49 * CR);  // contiguous [kk][c] for this s
  float* kb = kout + (size_t)b * (KKG * HW) + (size_t)s * HW + u;

  // ---- Phase 1: all 49 conv2 outputs (same FMA order as round 3 -> identical bits) ----
  float kv[49];
#pragma unroll
  for (int kk = 0; kk < 49; ++kk) {
    const float* wrow = wbase + kk * CR;
    float a0 = 0.f, a1 = 0.f, a2 = 0.f, a3 = 0.f;     // 4-way ILP split
#pragma unroll
    for (int c = 0; c < CR; c += 4) {
      a0 = fmaf(wrow[c + 0], t_reg[c + 0], a0);
      a1 = fmaf(wrow[c + 1], t_reg[c + 1], a1);
      a2 = fmaf(wrow[c + 2], t_reg[c + 2], a2);
      a3 = fmaf(wrow[c + 3], t_reg[c + 3], a3);
    }
    float v = b2[16 * kk + s] + ((a0 + a1) + (a2 + a3));
    kv[kk] = v;
    kb[(size_t)kk * (16 * HW)] = v;          // kout computed & written exactly once
  }

  // ---- Phase 2: 49 independent x_g taps (deep load batching) ----
  int yrow = u / 56;
  int col  = u - yrow * 56;
  const size_t bHW16 = (size_t)(b * HW) << 4;

  float acc[16];
#pragma unroll
  for (int i = 0; i < 16; ++i) acc[i] = 0.0f;

#pragma unroll
  for (int kk = 0; kk < 49; ++kk) {
    int t16 = 16 * kk + s;                   // scalar
    int d   = t16 / 49;                      // scalar (SALU magic-mul)
    int kkp = t16 - d * 49;
    int ki  = kkp / 7;
    int kj  = kkp - ki * 7;
    int yy = yrow + ki - 3, xx = col + kj - 3;
    float k = kv[kk];
    int off;
    if ((unsigned)yy < 56u && (unsigned)xx < 56u) {
      off = yy * 56 + xx;
    } else {
      off = 0;                               // safe address; k=0 kills the term
      k = 0.0f;
    }
    const float* xp = g_xg + (((size_t)d * NPIX + off) << 4) + bHW16;
    float4 x0 = *(const float4*)xp;
    float4 x1 = *(const float4*)(xp + 4);
    float4 x2 = *(const float4*)(xp + 8);
    float4 x3 = *(const float4*)(xp + 12);
    acc[0]  += k * x0.x;  acc[1]  += k * x0.y;
    acc[2]  += k * x0.z;  acc[3]  += k * x0.w;
    acc[4]  += k * x1.x;  acc[5]  += k * x1.y;
    acc[6]  += k * x1.z;  acc[7]  += k * x1.w;
    acc[8]  += k * x2.x;  acc[9]  += k * x2.y;
    acc[10] += k * x2.z;  acc[11] += k * x2.w;
    acc[12] += k * x3.x;  acc[13] += k * x3.y;
    acc[14] += k * x3.z;  acc[15] += k * x3.w;
  }

  // out channel c = 16*cg + s
  float* ob = out + (size_t)b * (C_IN * HW) + (size_t)s * HW + u;
#pragma unroll
  for (int cg = 0; cg < 16; ++cg) ob[(size_t)cg * (16 * HW)] = acc[cg];
}

extern "C" void kernel_launch(void* const* d_in, const int* in_sizes, int n_in,
                              void* d_out, int out_size, void* d_ws, size_t ws_size,
                              hipStream_t stream) {
  const float* x     = (const float*)d_in[0];
  const float* w1    = (const float*)d_in[1];
  const float* b1    = (const float*)d_in[2];
  const float* gamma = (const float*)d_in[3];
  const float* beta  = (const float*)d_in[4];
  const float* w2    = (const float*)d_in[5];
  const float* b2    = (const float*)d_in[6];

  float* out  = (float*)d_out;                       // (B,256,56,56)
  float* kout = out + (size_t)NB * C_IN * HW;        // (B,784,56,56) raw == (B,49,56,56,16)

  k1a_conv1<<<dim3(825), 256, 0, stream>>>(x, w1, w2);
  kRT<<<dim3(25, 80), 256, 0, stream>>>(x, b1);
  k45<<<dim3(16, 25, NB), 128, 0, stream>>>(gamma, beta, b2, kout, out);
}

// Round 7
// 135.835 us; speedup vs baseline: 1.7804x; 1.7804x over previous
//
#include <hip/hip_runtime.h>

// Problem constants (B,C,H,W)=(2,256,56,56), Cr=64, K=7, G=16, stride=1
#define HW     3136          // 56*56
#define C_IN   256
#define CR     64
#define KKG    784           // 49*16
#define NB     2             // batch
#define NPIX   6272          // NB*HW
#define NT25   25            // p-tiles of 256 over NPIX
#define BN_EPS 1e-5f

// Device-global scratch (fully rewritten every call; no cross-call state)
__device__ float g_P[4 * CR * NPIX];       // K-split conv1 partials [kc][o][p]
__device__ float g_T[CR * NPIX];           // conv1 output (pre-BN) [o][p]
__device__ float g_bs[2 * CR * NT25];      // per-block partial sum/sumsq [2][o][px]
__device__ float g_xg[16 * NPIX * 16];     // x transposed: [d][p][cg] = x[b][16cg+d][hw]
__device__ float g_w2s[16 * 49 * CR];      // w2 regrouped: [s][kk][c] = w2[16kk+s][c]

// ---------------- K1a: conv1 partials (o-tile 8, split-K 4), XCD-swizzled ----------------
// grid (825) 1-D, block 256.  (ROUND-0 VERIFIED CODE -- do not restructure: the split-K
// "extra" 12.8 MB g_P round-trip buys 800 blocks of latency hiding; the 200-block
// full-K fusion (round 2) regressed 124->133 us.)
__global__ __launch_bounds__(256) void k1a_conv1(const float* __restrict__ x,
                                                 const float* __restrict__ w1,
                                                 const float* __restrict__ w2) {
  int bid = blockIdx.x;
  if (bid >= 800) {
    int t = bid - 800;
    int idx = t * 256 + threadIdx.x;
    for (int j = idx; j < 16 * 49 * CR; j += 25 * 256) {
      int s  = j / 3136;                   // 49*64 = 3136 per s
      int r  = j - s * 3136;
      int kk = r >> 6;
      int c  = r & 63;                     // g_w2s[s][kk][c] = w2[(16kk+s)*64 + c]
      g_w2s[j] = w2[(16 * kk + s) * CR + c];
    }
    return;
  }
  int kc     = (bid & 7) >> 1;              // constant per XCD-pair
  int parity = bid & 1;
  int unit   = (bid >> 3) * 2 + parity;     // [0, 200)
  int o0     = (unit & 7) * 8;
  int pt     = unit >> 3;                   // [0, 25)
  int p      = pt * 256 + threadIdx.x;
  if (p >= NPIX) return;
  int b = p / HW;
  int u = p - b * HW;

  const float* xb = x + ((size_t)(b * C_IN + kc * 64)) * HW + u;
  const float* w  = w1 + kc * 64;           // w1[o*256 + kc*64 + c]

  float acc[8];
#pragma unroll
  for (int i = 0; i < 8; ++i) acc[i] = 0.0f;
#pragma unroll 8
  for (int c = 0; c < 64; ++c) {
    float xv = xb[(size_t)c * HW];          // coalesced across lanes, L2-resident slice
#pragma unroll
    for (int i = 0; i < 8; ++i)
      acc[i] += w[(o0 + i) * C_IN + c] * xv;  // wave-uniform -> s_load
  }
  float* pp = g_P + ((size_t)kc * CR + o0) * NPIX + p;
#pragma unroll
  for (int i = 0; i < 8; ++i) pp[(size_t)i * NPIX] = acc[i];
}

// ---------------- kRT: fused (reduce partials -> T + partial stats) | (transpose x) ----
// grid (25, 80), block 256.  (ROUND-0 VERIFIED CODE.)
__global__ __launch_bounds__(256) void kRT(const float* __restrict__ x,
                                           const float* __restrict__ b1) {
  int p = blockIdx.x * 256 + threadIdx.x;
  if (blockIdx.y < 64) {
    int o = blockIdx.y;
    bool valid = (p < NPIX);
    float v = 0.0f;
    if (valid) {
      v = b1[o]
        + g_P[((size_t)0 * CR + o) * NPIX + p]
        + g_P[((size_t)1 * CR + o) * NPIX + p]
        + g_P[((size_t)2 * CR + o) * NPIX + p]
        + g_P[((size_t)3 * CR + o) * NPIX + p];
      g_T[(size_t)o * NPIX + p] = v;
    }
    float s  = valid ? v : 0.0f;
    float s2 = valid ? v * v : 0.0f;
#pragma unroll
    for (int off = 32; off > 0; off >>= 1) {
      s  += __shfl_down(s, off);
      s2 += __shfl_down(s2, off);
    }
    __shared__ float sd[8];
    int lane = threadIdx.x & 63, wid = threadIdx.x >> 6;
    if (lane == 0) { sd[wid] = s; sd[4 + wid] = s2; }
    __syncthreads();
    if (threadIdx.x == 0) {
      g_bs[o * NT25 + blockIdx.x]             = sd[0] + sd[1] + sd[2] + sd[3];
      g_bs[CR * NT25 + o * NT25 + blockIdx.x] = sd[4] + sd[5] + sd[6] + sd[7];
    }
  } else {
    int d = blockIdx.y - 64;
    if (p >= NPIX) return;
    int b  = (p >= HW) ? 1 : 0;
    int hw = p - b * HW;
    const float* xp = x + ((size_t)(b * C_IN + d)) * HW + hw;
    float r[16];
#pragma unroll
    for (int cg = 0; cg < 16; ++cg)
      r[cg] = xp[(size_t)cg * (16 * HW)];
    float4* dst = (float4*)(g_xg + (((size_t)d * NPIX + p) << 4));
    dst[0] = make_float4(r[0], r[1], r[2], r[3]);
    dst[1] = make_float4(r[4], r[5], r[6], r[7]);
    dst[2] = make_float4(r[8], r[9], r[10], r[11]);
    dst[3] = make_float4(r[12], r[13], r[14], r[15]);
  }
}

// ---------------- k45: FUSED conv2 + involution, BOUNDED-GROUP phase split --------------
// History: round-3 interleaved version = 44.4 us (VALUBusy 18%, latency-bound).
// Round-4 cg-split = 2x FMA = 80 us. Round-6 full phase-split = kv[49]+hoisted loads ->
// 256 VGPR + 195 MB scratch spill = 162 us. This version: round-3 shell (grid (16,13,2),
// 256 thr, compute-once) with taps processed in GROUPS OF 4:
//   per group: issue 16 independent 16B x_g loads (addresses don't depend on kv) ->
//   compute 4 conv2 kv (256 FMA ~ 512 cyc, covers L2 latency) -> consume (64 FMA).
// '#pragma unroll 1' on the group loop bounds live state (~175 VGPR, no spill) and
// blocks the cross-group load hoisting that spilled in round 6. Same FMA count/order
// as round 3 -> bit-identical kout/out.
__global__ __launch_bounds__(256) void k45(const float* __restrict__ gamma,
                                           const float* __restrict__ beta,
                                           const float* __restrict__ b2,
                                           float* __restrict__ kout,
                                           float* __restrict__ out) {
  // BN finalize (same math/order as before)
  __shared__ float ssc[CR], ssh[CR];
  if (threadIdx.x < CR) {
    int o = threadIdx.x;
    float S = 0.f, S2 = 0.f;
#pragma unroll
    for (int px = 0; px < NT25; ++px) {
      S  += g_bs[o * NT25 + px];
      S2 += g_bs[CR * NT25 + o * NT25 + px];
    }
    const float invN = 1.0f / (float)NPIX;
    float mean = S * invN;
    float var  = S2 * invN - mean * mean;   // population var matches jnp.var
    float inv  = rsqrtf(var + BN_EPS);
    float sc   = gamma[o] * inv;
    ssc[o] = sc;
    ssh[o] = beta[o] - mean * sc;
  }
  __syncthreads();

  int u = blockIdx.y * 256 + threadIdx.x;     // [0, 3328); last tile partly idle
  if (u >= HW) return;                        // after the barrier
  int s = blockIdx.x;                         // wave-uniform
  int b = blockIdx.z;

  // Stage this pixel's BN+ReLU'd conv1 column in registers (coalesced across lanes).
  float t_reg[CR];
  const float* Tb = g_T + (size_t)b * HW + u;
#pragma unroll
  for (int c = 0; c < CR; ++c)
    t_reg[c] = fmaxf(fmaf(Tb[(size_t)c * NPIX], ssc[c], ssh[c]), 0.0f);

  const float* wbase = g_w2s + (size_t)s * (49 * CR);  // contiguous [kk][c] for this s
  float* kb = kout + (size_t)b * (KKG * HW) + (size_t)s * HW + u;

  int yrow = u / 56;
  int col  = u - yrow * 56;
  const size_t bHW16 = (size_t)(b * HW) << 4;

  float acc[16];
#pragma unroll
  for (int i = 0; i < 16; ++i) acc[i] = 0.0f;

#pragma unroll 1                             // rolled: bounds VGPR live range (round-6 fix)
  for (int g = 0; g < 48; g += 4) {
    // ---- issue 16 independent x_g loads for taps g..g+3 (addresses kv-independent) ----
    float4 ld[4][4];                         // static indices only -> registers
    float  msk[4];
#pragma unroll
    for (int j = 0; j < 4; ++j) {
      int kk  = g + j;
      int t16 = 16 * kk + s;                 // scalar
      int d   = t16 / 49;                    // scalar magic-mul
      int kkp = t16 - d * 49;
      int ki  = kkp / 7;
      int kj  = kkp - ki * 7;
      int yy = yrow + ki - 3, xx = col + kj - 3;
      bool ok = ((unsigned)yy < 56u) && ((unsigned)xx < 56u);
      int off = ok ? (yy * 56 + xx) : 0;     // safe address; msk kills OOB term
      msk[j] = ok ? 1.0f : 0.0f;
      const float* xp = g_xg + (((size_t)d * NPIX + off) << 4) + bHW16;
      ld[j][0] = *(const float4*)xp;
      ld[j][1] = *(const float4*)(xp + 4);
      ld[j][2] = *(const float4*)(xp + 8);
      ld[j][3] = *(const float4*)(xp + 12);
    }
    // ---- conv2 kv for taps g..g+3 (512 cyc of FMA covers the loads' latency) ----
    float kv4[4];
#pragma unroll
    for (int j = 0; j < 4; ++j) {
      int kk = g + j;
      const float* wrow = wbase + kk * CR;
      float a0 = 0.f, a1 = 0.f, a2 = 0.f, a3 = 0.f;   // 4-way ILP split
#pragma unroll
      for (int c = 0; c < CR; c += 4) {
        a0 = fmaf(wrow[c + 0], t_reg[c + 0], a0);
        a1 = fmaf(wrow[c + 1], t_reg[c + 1], a1);
        a2 = fmaf(wrow[c + 2], t_reg[c + 2], a2);
        a3 = fmaf(wrow[c + 3], t_reg[c + 3], a3);
      }
      float v = b2[16 * kk + s] + ((a0 + a1) + (a2 + a3));
      kb[(size_t)kk * (16 * HW)] = v;        // kout computed & written exactly once
      kv4[j] = v;
    }
    // ---- consume: 4 taps x 16 FMA ----
#pragma unroll
    for (int j = 0; j < 4; ++j) {
      float k = kv4[j] * msk[j];
      acc[0]  += k * ld[j][0].x;  acc[1]  += k * ld[j][0].y;
      acc[2]  += k * ld[j][0].z;  acc[3]  += k * ld[j][0].w;
      acc[4]  += k * ld[j][1].x;  acc[5]  += k * ld[j][1].y;
      acc[6]  += k * ld[j][1].z;  acc[7]  += k * ld[j][1].w;
      acc[8]  += k * ld[j][2].x;  acc[9]  += k * ld[j][2].y;
      acc[10] += k * ld[j][2].z;  acc[11] += k * ld[j][2].w;
      acc[12] += k * ld[j][3].x;  acc[13] += k * ld[j][3].y;
      acc[14] += k * ld[j][3].z;  acc[15] += k * ld[j][3].w;
    }
  }
  { // ---- tail tap kk = 48 ----
    int kk  = 48;
    int t16 = 16 * kk + s;
    int d   = t16 / 49;
    int kkp = t16 - d * 49;
    int ki  = kkp / 7;
    int kj  = kkp - ki * 7;
    int yy = yrow + ki - 3, xx = col + kj - 3;
    bool ok = ((unsigned)yy < 56u) && ((unsigned)xx < 56u);
    int off = ok ? (yy * 56 + xx) : 0;
    const float* xp = g_xg + (((size_t)d * NPIX + off) << 4) + bHW16;
    float4 x0 = *(const float4*)xp;
    float4 x1 = *(const float4*)(xp + 4);
    float4 x2 = *(const float4*)(xp + 8);
    float4 x3 = *(const float4*)(xp + 12);
    const float* wrow = wbase + kk * CR;
    float a0 = 0.f, a1 = 0.f, a2 = 0.f, a3 = 0.f;
#pragma unroll
    for (int c = 0; c < CR; c += 4) {
      a0 = fmaf(wrow[c + 0], t_reg[c + 0], a0);
      a1 = fmaf(wrow[c + 1], t_reg[c + 1], a1);
      a2 = fmaf(wrow[c + 2], t_reg[c + 2], a2);
      a3 = fmaf(wrow[c + 3], t_reg[c + 3], a3);
    }
    float v = b2[16 * kk + s] + ((a0 + a1) + (a2 + a3));
    kb[(size_t)kk * (16 * HW)] = v;
    float k = ok ? v : 0.0f;
    acc[0]  += k * x0.x;  acc[1]  += k * x0.y;
    acc[2]  += k * x0.z;  acc[3]  += k * x0.w;
    acc[4]  += k * x1.x;  acc[5]  += k * x1.y;
    acc[6]  += k * x1.z;  acc[7]  += k * x1.w;
    acc[8]  += k * x2.x;  acc[9]  += k * x2.y;
    acc[10] += k * x2.z;  acc[11] += k * x2.w;
    acc[12] += k * x3.x;  acc[13] += k * x3.y;
    acc[14] += k * x3.z;  acc[15] += k * x3.w;
  }

  // out channel c = 16*cg + s
  float* ob = out + (size_t)b * (C_IN * HW) + (size_t)s * HW + u;
#pragma unroll
  for (int cg = 0; cg < 16; ++cg) ob[(size_t)cg * (16 * HW)] = acc[cg];
}

extern "C" void kernel_launch(void* const* d_in, const int* in_sizes, int n_in,
                              void* d_out, int out_size, void* d_ws, size_t ws_size,
                              hipStream_t stream) {
  const float* x     = (const float*)d_in[0];
  const float* w1    = (const float*)d_in[1];
  const float* b1    = (const float*)d_in[2];
  const float* gamma = (const float*)d_in[3];
  const float* beta  = (const float*)d_in[4];
  const float* w2    = (const float*)d_in[5];
  const float* b2    = (const float*)d_in[6];

  float* out  = (float*)d_out;                       // (B,256,56,56)
  float* kout = out + (size_t)NB * C_IN * HW;        // (B,784,56,56) raw == (B,49,56,56,16)

  k1a_conv1<<<dim3(825), 256, 0, stream>>>(x, w1, w2);
  kRT<<<dim3(25, 80), 256, 0, stream>>>(x, b1);
  k45<<<dim3(16, 13, NB), 256, 0, stream>>>(gamma, beta, b2, kout, out);
}